// Round 1
// baseline (1052.328 us; speedup 1.0000x reference)
//
#include <hip/hip_runtime.h>
#include <math.h>

#define N_IMG 6
#define CIN   256
#define H_IN  32
#define W_IN  88
#define SP    2816      // 32*88
#define COUTC 80
#define EPSBN 1e-5f

// ---------------- weight transposes ----------------
// w (OIHW: [256][256][3][3]) -> wT ([tap][ic][oc])
__global__ __launch_bounds__(256) void transpose_w33(const float* __restrict__ w,
                                                     float* __restrict__ wT) {
  int idx = blockIdx.x * 256 + threadIdx.x;
  if (idx >= 9 * CIN * CIN) return;
  int oc  = idx & 255;
  int ic  = (idx >> 8) & 255;
  int tap = idx >> 16;
  wT[idx] = w[(oc * CIN + ic) * 9 + tap];
}

// w3 ([80][256]) -> wT3 ([ic][oc])
__global__ __launch_bounds__(256) void transpose_w11(const float* __restrict__ w,
                                                     float* __restrict__ wT) {
  int idx = blockIdx.x * 256 + threadIdx.x;
  if (idx >= CIN * COUTC) return;
  int oc = idx % COUTC;
  int ic = idx / COUTC;
  wT[idx] = w[oc * CIN + ic];
}

// ---------------- 3x3 conv + BN + ReLU (fp32 implicit GEMM) ----------------
// tile: 128 spatial x 64 oc, micro-tile 8(sp, split 4+4) x 4(oc)
__global__ __launch_bounds__(256) void conv3x3_bn_relu(
    const float* __restrict__ x, const float* __restrict__ wT,
    const float* __restrict__ bias, const float* __restrict__ gamma,
    const float* __restrict__ beta, const float* __restrict__ bnm,
    const float* __restrict__ bnv, float* __restrict__ out)
{
  const int m0  = blockIdx.x * 128;
  const int n0  = blockIdx.y * 64;
  const int img = blockIdx.z;
  const int tid = threadIdx.x;

  __shared__ float As[16][128];
  __shared__ float Bs[16][64];

  const float* xb = x + (size_t)img * CIN * SP;

  const int mmL  = tid & 127;
  const int kk0A = tid >> 7;            // 0..1
  const int mL = m0 + mmL;
  const int hL = mL / 88;
  const int wL = mL - hL * 88;
  const int nnL  = tid & 63;
  const int kk0B = tid >> 6;            // 0..3
  const int tx = tid & 15;
  const int ty = tid >> 4;

  float acc[4][8];
  #pragma unroll
  for (int j = 0; j < 4; ++j)
    #pragma unroll
    for (int i = 0; i < 8; ++i) acc[j][i] = 0.f;

  for (int tap = 0; tap < 9; ++tap) {
    const int dy = tap / 3 - 1;
    const int dx = tap - (tap / 3) * 3 - 1;
    const int hy = hL + dy, wx = wL + dx;
    const bool inb = (hy >= 0) && (hy < H_IN) && (wx >= 0) && (wx < W_IN);
    const int saddr = hy * 88 + wx;
    const float* wTt = wT + (size_t)tap * CIN * CIN;

    for (int kc = 0; kc < CIN / 16; ++kc) {
      #pragma unroll
      for (int i = 0; i < 8; ++i) {
        int kk = kk0A + i * 2;
        float v = 0.f;
        if (inb) v = xb[(size_t)(kc * 16 + kk) * SP + saddr];
        As[kk][mmL] = v;
      }
      #pragma unroll
      for (int i = 0; i < 4; ++i) {
        int kk = kk0B + i * 4;
        Bs[kk][nnL] = wTt[(size_t)(kc * 16 + kk) * CIN + n0 + nnL];
      }
      __syncthreads();
      #pragma unroll
      for (int k = 0; k < 16; ++k) {
        const float4 a0 = *(const float4*)(&As[k][tx * 4]);
        const float4 a1 = *(const float4*)(&As[k][64 + tx * 4]);
        const float4 b  = *(const float4*)(&Bs[k][ty * 4]);
        const float av[8] = {a0.x, a0.y, a0.z, a0.w, a1.x, a1.y, a1.z, a1.w};
        const float bv[4] = {b.x, b.y, b.z, b.w};
        #pragma unroll
        for (int j = 0; j < 4; ++j)
          #pragma unroll
          for (int i = 0; i < 8; ++i)
            acc[j][i] = fmaf(av[i], bv[j], acc[j][i]);
      }
      __syncthreads();
    }
  }

  #pragma unroll
  for (int j = 0; j < 4; ++j) {
    const int oc = n0 + ty * 4 + j;
    const float sc = gamma[oc] / sqrtf(bnv[oc] + EPSBN);
    const float sh = (bias[oc] - bnm[oc]) * sc + beta[oc];
    float* ob = out + ((size_t)img * CIN + oc) * SP + m0;
    #pragma unroll
    for (int half = 0; half < 2; ++half) {
      float4 v;
      v.x = fmaxf(fmaf(acc[j][half * 4 + 0], sc, sh), 0.f);
      v.y = fmaxf(fmaf(acc[j][half * 4 + 1], sc, sh), 0.f);
      v.z = fmaxf(fmaf(acc[j][half * 4 + 2], sc, sh), 0.f);
      v.w = fmaxf(fmaf(acc[j][half * 4 + 3], sc, sh), 0.f);
      *(float4*)(&ob[half * 64 + tx * 4]) = v;
    }
  }
}

// ---------------- 1x1 conv (256->80) + bias, output NHWC ----------------
// tile: 64 spatial x 80 oc, micro-tile 4(sp) x 5(oc)
__global__ __launch_bounds__(256) void conv1x1_bias_nhwc(
    const float* __restrict__ x, const float* __restrict__ wT,
    const float* __restrict__ bias, float* __restrict__ feat)
{
  const int m0  = blockIdx.x * 64;
  const int img = blockIdx.y;
  const int tid = threadIdx.x;

  __shared__ float As[16][64];
  __shared__ float Bs[16][80];

  const int mmL  = tid & 63;
  const int kk0A = tid >> 6;   // 0..3
  const int tx = tid & 15;
  const int ty = tid >> 4;

  float acc[5][4];
  #pragma unroll
  for (int j = 0; j < 5; ++j)
    #pragma unroll
    for (int i = 0; i < 4; ++i) acc[j][i] = 0.f;

  const float* xb = x + (size_t)img * CIN * SP + m0;

  for (int kc = 0; kc < CIN / 16; ++kc) {
    #pragma unroll
    for (int i = 0; i < 4; ++i) {
      int kk = kk0A + i * 4;
      As[kk][mmL] = xb[(size_t)(kc * 16 + kk) * SP + mmL];
    }
    #pragma unroll
    for (int i = 0; i < 5; ++i) {
      int idx = tid + i * 256;          // 0..1279
      int kk = idx / 80;
      int oc = idx - kk * 80;
      Bs[kk][oc] = wT[(size_t)(kc * 16 + kk) * COUTC + oc];
    }
    __syncthreads();
    #pragma unroll
    for (int k = 0; k < 16; ++k) {
      const float4 a = *(const float4*)(&As[k][tx * 4]);
      const float av[4] = {a.x, a.y, a.z, a.w};
      #pragma unroll
      for (int j = 0; j < 5; ++j) {
        const float bv = Bs[k][ty * 5 + j];
        #pragma unroll
        for (int i = 0; i < 4; ++i)
          acc[j][i] = fmaf(av[i], bv, acc[j][i]);
      }
    }
    __syncthreads();
  }

  #pragma unroll
  for (int j = 0; j < 5; ++j) {
    const int oc = ty * 5 + j;
    const float bb = bias[oc];
    #pragma unroll
    for (int i = 0; i < 4; ++i) {
      const int m = m0 + tx * 4 + i;
      feat[((size_t)img * SP + m) * COUTC + oc] = acc[j][i] + bb;
    }
  }
}

// ---------------- projection + bilinear + max over cams + mean over z ----------------
// block: 320 threads = 4 cells x 80 channels. tmp layout [cell(16384)][c(80)]
__global__ __launch_bounds__(320) void bev_sample(
    const float* __restrict__ feat, const float* __restrict__ l2i,
    float* __restrict__ tmp)
{
  __shared__ int4   eo[240];
  __shared__ float4 ew[240];
  const int tid = threadIdx.x;
  const int cellBase = blockIdx.x * 4;

  if (tid < 240) {
    const int cell = tid / 60;
    const int e = tid - cell * 60;
    const int n = e / 10;
    const int z = e - n * 10;
    const int cid = cellBase + cell;
    const int gix = cid >> 7;
    const int giy = cid & 127;
    const float X = (float)(-50.8 + (double)gix * (101.6 / 127.0));
    const float Y = (float)(-50.8 + (double)giy * (101.6 / 127.0));
    const float Z = (float)(-4.6 + (double)z * (7.2 / 9.0));
    const float* M = l2i + n * 16;
    const float pw = M[0] * X + M[1] * Y + M[2] * Z + M[3];
    const float ph = M[4] * X + M[5] * Y + M[6] * Z + M[7];
    const float d  = M[8] * X + M[9] * Y + M[10] * Z + M[11];
    const float px = pw / d;
    const float py = ph / d;
    const bool on_img = (px < 704.f) && (px > 0.f) && (py < 256.f) && (py > 0.f) && (d > 0.1f);
    const float gx = px / 704.f * 2.f - 1.f;
    const float gy = py / 256.f * 2.f - 1.f;
    const float ixf = (gx + 1.f) * 0.5f * 87.f;
    const float iyf = (gy + 1.f) * 0.5f * 31.f;
    const float ix0 = floorf(ixf);
    const float iy0 = floorf(iyf);
    const float wx1 = ixf - ix0;
    const float wy1 = iyf - iy0;
    const float ix1 = ix0 + 1.f, iy1 = iy0 + 1.f;
    float w00 = (1.f - wy1) * (1.f - wx1);
    float w01 = (1.f - wy1) * wx1;
    float w10 = wy1 * (1.f - wx1);
    float w11 = wy1 * wx1;
    const bool vx0 = (ix0 >= 0.f) && (ix0 < 88.f);
    const bool vx1 = (ix1 >= 0.f) && (ix1 < 88.f);
    const bool vy0 = (iy0 >= 0.f) && (iy0 < 32.f);
    const bool vy1 = (iy1 >= 0.f) && (iy1 < 32.f);
    if (!(on_img && vy0 && vx0)) w00 = 0.f;
    if (!(on_img && vy0 && vx1)) w01 = 0.f;
    if (!(on_img && vy1 && vx0)) w10 = 0.f;
    if (!(on_img && vy1 && vx1)) w11 = 0.f;
    // NaN-safe clamps (fmaxf(NaN,0)=0)
    const int i0 = (int)fminf(fmaxf(ix0, 0.f), 87.f);
    const int i1 = (int)fminf(fmaxf(ix1, 0.f), 87.f);
    const int j0 = (int)fminf(fmaxf(iy0, 0.f), 31.f);
    const int j1 = (int)fminf(fmaxf(iy1, 0.f), 31.f);
    const int base = n * SP;
    eo[tid] = make_int4((base + j0 * 88 + i0) * COUTC,
                        (base + j0 * 88 + i1) * COUTC,
                        (base + j1 * 88 + i0) * COUTC,
                        (base + j1 * 88 + i1) * COUTC);
    ew[tid] = make_float4(w00, w01, w10, w11);
  }
  __syncthreads();

  const int c = tid % 80;
  const int cell = tid / 80;
  const int ebase = cell * 60;
  float acc = 0.f;
  for (int z = 0; z < 10; ++z) {
    float mx = -INFINITY;
    #pragma unroll
    for (int n = 0; n < 6; ++n) {
      const int4   o = eo[ebase + n * 10 + z];
      const float4 w = ew[ebase + n * 10 + z];
      float v = w.x * feat[o.x + c];
      v = fmaf(w.y, feat[o.y + c], v);
      v = fmaf(w.z, feat[o.z + c], v);
      v = fmaf(w.w, feat[o.w + c], v);
      mx = fmaxf(mx, v);
    }
    acc += mx;
  }
  tmp[(size_t)(cellBase + cell) * COUTC + c] = acc / 10.f;
}

// ---------------- [16384][80] -> [80][16384] transpose ----------------
__global__ __launch_bounds__(256) void bev_transpose(const float* __restrict__ tmp,
                                                     float* __restrict__ out)
{
  __shared__ float tile[32][33];
  const int mBase = blockIdx.x * 32;
  const int cBase = blockIdx.y * 32;
  const int tx = threadIdx.x & 31;
  const int ty = threadIdx.x >> 5;   // 0..7
  for (int i = ty; i < 32; i += 8) {
    const int cc = cBase + tx;
    tile[i][tx] = (cc < COUTC) ? tmp[(size_t)(mBase + i) * COUTC + cc] : 0.f;
  }
  __syncthreads();
  for (int i = ty; i < 32; i += 8) {
    const int cc = cBase + i;
    if (cc < COUTC) out[(size_t)cc * 16384 + mBase + tx] = tile[tx][i];
  }
}

extern "C" void kernel_launch(void* const* d_in, const int* in_sizes, int n_in,
                              void* d_out, int out_size, void* d_ws, size_t ws_size,
                              hipStream_t stream)
{
  const float* img = (const float*)d_in[0];
  const float* l2i = (const float*)d_in[1];
  const float* w1  = (const float*)d_in[2];
  const float* b1  = (const float*)d_in[3];
  const float* g1  = (const float*)d_in[4];
  const float* be1 = (const float*)d_in[5];
  const float* m1  = (const float*)d_in[6];
  const float* v1  = (const float*)d_in[7];
  const float* w2  = (const float*)d_in[8];
  const float* b2  = (const float*)d_in[9];
  const float* g2  = (const float*)d_in[10];
  const float* be2 = (const float*)d_in[11];
  const float* m2  = (const float*)d_in[12];
  const float* v2  = (const float*)d_in[13];
  const float* w3  = (const float*)d_in[14];
  const float* b3  = (const float*)d_in[15];

  float* ws   = (float*)d_ws;
  float* wT1  = ws;                   // 589824
  float* wT2  = wT1 + 589824;         // 589824
  float* wT3  = wT2 + 589824;         // 20480
  float* x1   = wT3 + 20480;          // 4866048
  float* x2   = x1  + 4866048;        // 4866048
  float* feat = x2  + 4866048;        // 6*2816*80 = 1351680
  float* tmp  = feat + 1351680;       // 16384*80 = 1310720
  float* outp = (float*)d_out;

  transpose_w33<<<2304, 256, 0, stream>>>(w1, wT1);
  transpose_w33<<<2304, 256, 0, stream>>>(w2, wT2);
  transpose_w11<<<80, 256, 0, stream>>>(w3, wT3);

  conv3x3_bn_relu<<<dim3(22, 4, 6), 256, 0, stream>>>(img, wT1, b1, g1, be1, m1, v1, x1);
  conv3x3_bn_relu<<<dim3(22, 4, 6), 256, 0, stream>>>(x1, wT2, b2, g2, be2, m2, v2, x2);
  conv1x1_bias_nhwc<<<dim3(44, 6), 256, 0, stream>>>(x2, wT3, b3, feat);

  bev_sample<<<4096, 320, 0, stream>>>(feat, l2i, tmp);
  bev_transpose<<<dim3(512, 3), 256, 0, stream>>>(tmp, outp);
}

// Round 2
// 260.518 us; speedup vs baseline: 4.0394x; 4.0394x over previous
//
#include <hip/hip_runtime.h>
#include <math.h>

#define N_IMG 6
#define CIN   256
#define H_IN  32
#define W_IN  88
#define SP    2816      // 32*88
#define COUTC 80
#define EPSBN 1e-5f

typedef _Float16 half8 __attribute__((ext_vector_type(8)));
typedef float floatx4 __attribute__((ext_vector_type(4)));

// ---------------- weight prep ----------------
// w (OIHW [256][256][3][3]) -> fp16 [oc][tap][ic]
__global__ __launch_bounds__(256) void prep_w33(const float* __restrict__ w,
                                                _Float16* __restrict__ wT) {
  int idx = blockIdx.x * 256 + threadIdx.x;
  if (idx >= 9 * CIN * CIN) return;
  int oc  = idx / 2304;
  int r   = idx - oc * 2304;
  int tap = r >> 8;
  int ic  = r & 255;
  wT[idx] = (_Float16)w[(oc * CIN + ic) * 9 + tap];
}

// w3 [80][256] -> fp16 [oc][ic] (plain cast copy)
__global__ __launch_bounds__(256) void prep_w11(const float* __restrict__ w,
                                                _Float16* __restrict__ wT) {
  int idx = blockIdx.x * 256 + threadIdx.x;
  if (idx >= CIN * COUTC) return;
  wT[idx] = (_Float16)w[idx];
}

// img fp32 NCHW -> fp16 NHWC
__global__ __launch_bounds__(256) void nchw_to_nhwc(const float* __restrict__ img,
                                                    _Float16* __restrict__ x0) {
  __shared__ float t[64][65];
  const int sp0 = blockIdx.x * 64;
  const int ic0 = blockIdx.y * 64;
  const int im  = blockIdx.z;
  const int tx = threadIdx.x & 63;
  const int ty = threadIdx.x >> 6;   // 0..3
  for (int r = ty; r < 64; r += 4)
    t[r][tx] = img[((size_t)(im * CIN + ic0 + r)) * SP + sp0 + tx];
  __syncthreads();
  for (int r = ty; r < 64; r += 4)
    x0[((size_t)im * SP + sp0 + r) * CIN + ic0 + tx] = (_Float16)t[tx][r];
}

// ---------------- 3x3 conv + BN + ReLU, fp16 MFMA implicit GEMM ----------------
// block: 256 threads (4 waves). tile 128(sp) x 128(oc), BK=64. wave = 64x64.
__global__ __launch_bounds__(256) void conv3x3_mfma(
    const _Float16* __restrict__ x, const _Float16* __restrict__ wT,
    const float* __restrict__ bias, const float* __restrict__ gamma,
    const float* __restrict__ beta, const float* __restrict__ bnm,
    const float* __restrict__ bnv, _Float16* __restrict__ out)
{
  __shared__ _Float16 As[128 * 72];   // [m][k] pitch 72 (pad: 2-way banks = free)
  __shared__ _Float16 Bs[128 * 72];   // [oc][k] pitch 72

  const int tid = threadIdx.x;
  const int m0 = blockIdx.x * 128;
  const int n0 = blockIdx.y * 128;
  const int im = blockIdx.z;

  // staging: 1024 chunks of 8 halfs per tile, 4 per thread
  int rr[4], kk4[4], hh[4], ww[4];
  #pragma unroll
  for (int i = 0; i < 4; ++i) {
    const int c = tid + 256 * i;
    rr[i]  = c >> 3;
    kk4[i] = (c & 7) * 8;
    const int m = m0 + rr[i];
    hh[i] = m / 88;
    ww[i] = m - hh[i] * 88;
  }
  const _Float16* xim = x + (size_t)im * SP * CIN;

  const int lane = tid & 63;
  const int wv = tid >> 6;
  const int mw = (wv & 1) * 64;
  const int nw = (wv >> 1) * 64;
  const int fr = lane & 15;
  const int q8 = (lane >> 4) * 8;
  const int q4 = (lane >> 4) * 4;

  floatx4 acc[4][4];
  #pragma unroll
  for (int i = 0; i < 4; ++i)
    #pragma unroll
    for (int j = 0; j < 4; ++j) {
      acc[i][j][0] = 0.f; acc[i][j][1] = 0.f; acc[i][j][2] = 0.f; acc[i][j][3] = 0.f;
    }

  for (int tap = 0; tap < 9; ++tap) {
    const int dy = tap / 3 - 1;
    const int dx = tap - (tap / 3) * 3 - 1;
    bool val[4]; int sp[4];
    #pragma unroll
    for (int i = 0; i < 4; ++i) {
      const int hy = hh[i] + dy, wx = ww[i] + dx;
      val[i] = (hy >= 0) && (hy < H_IN) && (wx >= 0) && (wx < W_IN);
      sp[i] = hy * 88 + wx;
    }

    for (int icc = 0; icc < 256; icc += 64) {
      half8 av[4], bv[4];
      #pragma unroll
      for (int i = 0; i < 4; ++i) {
        half8 z = {};
        av[i] = val[i] ? *(const half8*)(xim + (size_t)sp[i] * CIN + icc + kk4[i]) : z;
        bv[i] = *(const half8*)(wT + (size_t)(n0 + rr[i]) * 2304 + tap * 256 + icc + kk4[i]);
      }
      #pragma unroll
      for (int i = 0; i < 4; ++i) {
        *(half8*)(&As[rr[i] * 72 + kk4[i]]) = av[i];
        *(half8*)(&Bs[rr[i] * 72 + kk4[i]]) = bv[i];
      }
      __syncthreads();

      const _Float16* Ab = &As[(mw + fr) * 72 + q8];
      const _Float16* Bb = &Bs[(nw + fr) * 72 + q8];
      #pragma unroll
      for (int ks = 0; ks < 2; ++ks) {
        half8 af[4], bf[4];
        #pragma unroll
        for (int i = 0; i < 4; ++i) af[i] = *(const half8*)(Ab + i * (16 * 72) + ks * 32);
        #pragma unroll
        for (int j = 0; j < 4; ++j) bf[j] = *(const half8*)(Bb + j * (16 * 72) + ks * 32);
        #pragma unroll
        for (int i = 0; i < 4; ++i)
          #pragma unroll
          for (int j = 0; j < 4; ++j)
            acc[i][j] = __builtin_amdgcn_mfma_f32_16x16x32_f16(af[i], bf[j], acc[i][j], 0, 0, 0);
      }
      __syncthreads();
    }
  }

  // epilogue: BN + ReLU, store fp16 NHWC
  #pragma unroll
  for (int j = 0; j < 4; ++j) {
    const int oc = n0 + nw + j * 16 + fr;
    const float sc = gamma[oc] * rsqrtf(bnv[oc] + EPSBN);
    const float sh = (bias[oc] - bnm[oc]) * sc + beta[oc];
    #pragma unroll
    for (int i = 0; i < 4; ++i) {
      const int mbase = m0 + mw + i * 16 + q4;
      #pragma unroll
      for (int r = 0; r < 4; ++r) {
        const float v = fmaxf(fmaf(acc[i][j][r], sc, sh), 0.f);
        out[((size_t)im * SP + mbase + r) * CIN + oc] = (_Float16)v;
      }
    }
  }
}

// ---------------- 1x1 conv (256->80) + bias, fp16 MFMA, NHWC fp32 out ----------------
// block: 256 threads (4 waves). tile 128(sp flat) x 80(oc). wave = 32x80.
__global__ __launch_bounds__(256) void conv1x1_mfma(
    const _Float16* __restrict__ x, const _Float16* __restrict__ wT,
    const float* __restrict__ bias, float* __restrict__ feat)
{
  __shared__ _Float16 As[128 * 72];
  __shared__ _Float16 Bs[80 * 72];

  const int tid = threadIdx.x;
  const int m0 = blockIdx.x * 128;

  int rr[4], kk4[4];
  #pragma unroll
  for (int i = 0; i < 4; ++i) {
    const int c = tid + 256 * i;
    rr[i]  = c >> 3;
    kk4[i] = (c & 7) * 8;
  }
  // B staging: 640 chunks
  const int rB0 = tid >> 3,         kB0 = (tid & 7) * 8;
  const int rB1 = (tid + 256) >> 3, kB1 = kB0;
  const int rB2 = (tid + 512) >> 3, kB2 = kB0;

  const int lane = tid & 63;
  const int wv = tid >> 6;
  const int mw = wv * 32;
  const int fr = lane & 15;
  const int q8 = (lane >> 4) * 8;
  const int q4 = (lane >> 4) * 4;

  floatx4 acc[2][5];
  #pragma unroll
  for (int i = 0; i < 2; ++i)
    #pragma unroll
    for (int j = 0; j < 5; ++j) {
      acc[i][j][0] = 0.f; acc[i][j][1] = 0.f; acc[i][j][2] = 0.f; acc[i][j][3] = 0.f;
    }

  for (int icc = 0; icc < 256; icc += 64) {
    half8 av[4];
    #pragma unroll
    for (int i = 0; i < 4; ++i)
      av[i] = *(const half8*)(x + (size_t)(m0 + rr[i]) * CIN + icc + kk4[i]);
    half8 b0 = *(const half8*)(wT + (size_t)rB0 * CIN + icc + kB0);
    half8 b1 = *(const half8*)(wT + (size_t)rB1 * CIN + icc + kB1);
    half8 b2 = {};
    if (tid < 128) b2 = *(const half8*)(wT + (size_t)rB2 * CIN + icc + kB2);

    #pragma unroll
    for (int i = 0; i < 4; ++i)
      *(half8*)(&As[rr[i] * 72 + kk4[i]]) = av[i];
    *(half8*)(&Bs[rB0 * 72 + kB0]) = b0;
    *(half8*)(&Bs[rB1 * 72 + kB1]) = b1;
    if (tid < 128) *(half8*)(&Bs[rB2 * 72 + kB2]) = b2;
    __syncthreads();

    const _Float16* Ab = &As[(mw + fr) * 72 + q8];
    const _Float16* Bb = &Bs[fr * 72 + q8];
    #pragma unroll
    for (int ks = 0; ks < 2; ++ks) {
      half8 af[2], bf[5];
      #pragma unroll
      for (int i = 0; i < 2; ++i) af[i] = *(const half8*)(Ab + i * (16 * 72) + ks * 32);
      #pragma unroll
      for (int j = 0; j < 5; ++j) bf[j] = *(const half8*)(Bb + j * (16 * 72) + ks * 32);
      #pragma unroll
      for (int i = 0; i < 2; ++i)
        #pragma unroll
        for (int j = 0; j < 5; ++j)
          acc[i][j] = __builtin_amdgcn_mfma_f32_16x16x32_f16(af[i], bf[j], acc[i][j], 0, 0, 0);
    }
    __syncthreads();
  }

  #pragma unroll
  for (int j = 0; j < 5; ++j) {
    const int oc = j * 16 + fr;
    const float bb = bias[oc];
    #pragma unroll
    for (int i = 0; i < 2; ++i) {
      const int mbase = m0 + mw + i * 16 + q4;
      #pragma unroll
      for (int r = 0; r < 4; ++r)
        feat[(size_t)(mbase + r) * COUTC + oc] = acc[i][j][r] + bb;
    }
  }
}

// ---------------- projection + bilinear + max over cams + mean over z ----------------
// block: 320 threads = 4 cells x 80 channels. tmp layout [cell(16384)][c(80)]
__global__ __launch_bounds__(320) void bev_sample(
    const float* __restrict__ feat, const float* __restrict__ l2i,
    float* __restrict__ tmp)
{
  __shared__ int4   eo[240];
  __shared__ float4 ew[240];
  const int tid = threadIdx.x;
  const int cellBase = blockIdx.x * 4;

  if (tid < 240) {
    const int cell = tid / 60;
    const int e = tid - cell * 60;
    const int n = e / 10;
    const int z = e - n * 10;
    const int cid = cellBase + cell;
    const int gix = cid >> 7;
    const int giy = cid & 127;
    const float X = (float)(-50.8 + (double)gix * (101.6 / 127.0));
    const float Y = (float)(-50.8 + (double)giy * (101.6 / 127.0));
    const float Z = (float)(-4.6 + (double)z * (7.2 / 9.0));
    const float* M = l2i + n * 16;
    const float pw = M[0] * X + M[1] * Y + M[2] * Z + M[3];
    const float ph = M[4] * X + M[5] * Y + M[6] * Z + M[7];
    const float d  = M[8] * X + M[9] * Y + M[10] * Z + M[11];
    const float px = pw / d;
    const float py = ph / d;
    const bool on_img = (px < 704.f) && (px > 0.f) && (py < 256.f) && (py > 0.f) && (d > 0.1f);
    const float gx = px / 704.f * 2.f - 1.f;
    const float gy = py / 256.f * 2.f - 1.f;
    const float ixf = (gx + 1.f) * 0.5f * 87.f;
    const float iyf = (gy + 1.f) * 0.5f * 31.f;
    const float ix0 = floorf(ixf);
    const float iy0 = floorf(iyf);
    const float wx1 = ixf - ix0;
    const float wy1 = iyf - iy0;
    const float ix1 = ix0 + 1.f, iy1 = iy0 + 1.f;
    float w00 = (1.f - wy1) * (1.f - wx1);
    float w01 = (1.f - wy1) * wx1;
    float w10 = wy1 * (1.f - wx1);
    float w11 = wy1 * wx1;
    const bool vx0 = (ix0 >= 0.f) && (ix0 < 88.f);
    const bool vx1 = (ix1 >= 0.f) && (ix1 < 88.f);
    const bool vy0 = (iy0 >= 0.f) && (iy0 < 32.f);
    const bool vy1 = (iy1 >= 0.f) && (iy1 < 32.f);
    if (!(on_img && vy0 && vx0)) w00 = 0.f;
    if (!(on_img && vy0 && vx1)) w01 = 0.f;
    if (!(on_img && vy1 && vx0)) w10 = 0.f;
    if (!(on_img && vy1 && vx1)) w11 = 0.f;
    const int i0 = (int)fminf(fmaxf(ix0, 0.f), 87.f);
    const int i1 = (int)fminf(fmaxf(ix1, 0.f), 87.f);
    const int j0 = (int)fminf(fmaxf(iy0, 0.f), 31.f);
    const int j1 = (int)fminf(fmaxf(iy1, 0.f), 31.f);
    const int base = n * SP;
    eo[tid] = make_int4((base + j0 * 88 + i0) * COUTC,
                        (base + j0 * 88 + i1) * COUTC,
                        (base + j1 * 88 + i0) * COUTC,
                        (base + j1 * 88 + i1) * COUTC);
    ew[tid] = make_float4(w00, w01, w10, w11);
  }
  __syncthreads();

  const int c = tid % 80;
  const int cell = tid / 80;
  const int ebase = cell * 60;
  float acc = 0.f;
  for (int z = 0; z < 10; ++z) {
    float mx = -INFINITY;
    #pragma unroll
    for (int n = 0; n < 6; ++n) {
      const int4   o = eo[ebase + n * 10 + z];
      const float4 w = ew[ebase + n * 10 + z];
      float v = w.x * feat[o.x + c];
      v = fmaf(w.y, feat[o.y + c], v);
      v = fmaf(w.z, feat[o.z + c], v);
      v = fmaf(w.w, feat[o.w + c], v);
      mx = fmaxf(mx, v);
    }
    acc += mx;
  }
  tmp[(size_t)(cellBase + cell) * COUTC + c] = acc / 10.f;
}

// ---------------- [16384][80] -> [80][16384] transpose ----------------
__global__ __launch_bounds__(256) void bev_transpose(const float* __restrict__ tmp,
                                                     float* __restrict__ out)
{
  __shared__ float tile[32][33];
  const int mBase = blockIdx.x * 32;
  const int cBase = blockIdx.y * 32;
  const int tx = threadIdx.x & 31;
  const int ty = threadIdx.x >> 5;   // 0..7
  for (int i = ty; i < 32; i += 8) {
    const int cc = cBase + tx;
    tile[i][tx] = (cc < COUTC) ? tmp[(size_t)(mBase + i) * COUTC + cc] : 0.f;
  }
  __syncthreads();
  for (int i = ty; i < 32; i += 8) {
    const int cc = cBase + i;
    if (cc < COUTC) out[(size_t)cc * 16384 + mBase + tx] = tile[tx][i];
  }
}

extern "C" void kernel_launch(void* const* d_in, const int* in_sizes, int n_in,
                              void* d_out, int out_size, void* d_ws, size_t ws_size,
                              hipStream_t stream)
{
  const float* img = (const float*)d_in[0];
  const float* l2i = (const float*)d_in[1];
  const float* w1  = (const float*)d_in[2];
  const float* b1  = (const float*)d_in[3];
  const float* g1  = (const float*)d_in[4];
  const float* be1 = (const float*)d_in[5];
  const float* m1  = (const float*)d_in[6];
  const float* v1  = (const float*)d_in[7];
  const float* w2  = (const float*)d_in[8];
  const float* b2  = (const float*)d_in[9];
  const float* g2  = (const float*)d_in[10];
  const float* be2 = (const float*)d_in[11];
  const float* m2  = (const float*)d_in[12];
  const float* v2  = (const float*)d_in[13];
  const float* w3  = (const float*)d_in[14];
  const float* b3  = (const float*)d_in[15];

  char* ws = (char*)d_ws;
  _Float16* wT1h = (_Float16*)ws;                    ws += 9 * CIN * CIN * 2;       // 1179648 B
  _Float16* wT2h = (_Float16*)ws;                    ws += 9 * CIN * CIN * 2;
  _Float16* wT3h = (_Float16*)ws;                    ws += CIN * COUTC * 2;         // 40960 B
  _Float16* x0   = (_Float16*)ws;                    ws += (size_t)N_IMG * SP * CIN * 2;
  _Float16* x1h  = (_Float16*)ws;                    ws += (size_t)N_IMG * SP * CIN * 2;
  _Float16* x2h  = (_Float16*)ws;                    ws += (size_t)N_IMG * SP * CIN * 2;
  float*    feat = (float*)ws;                       ws += (size_t)N_IMG * SP * COUTC * 4;
  float*    tmp  = (float*)ws;
  float*    outp = (float*)d_out;

  prep_w33<<<2304, 256, 0, stream>>>(w1, wT1h);
  prep_w33<<<2304, 256, 0, stream>>>(w2, wT2h);
  prep_w11<<<80, 256, 0, stream>>>(w3, wT3h);
  nchw_to_nhwc<<<dim3(44, 4, 6), 256, 0, stream>>>(img, x0);

  conv3x3_mfma<<<dim3(22, 2, 6), 256, 0, stream>>>(x0, wT1h, b1, g1, be1, m1, v1, x1h);
  conv3x3_mfma<<<dim3(22, 2, 6), 256, 0, stream>>>(x1h, wT2h, b2, g2, be2, m2, v2, x2h);
  conv1x1_mfma<<<132, 256, 0, stream>>>(x2h, wT3h, b3, feat);

  bev_sample<<<4096, 320, 0, stream>>>(feat, l2i, tmp);
  bev_transpose<<<dim3(512, 3), 256, 0, stream>>>(tmp, outp);
}